// Round 2
// baseline (1244.224 us; speedup 1.0000x reference)
//
#include <hip/hip_runtime.h>
#include <cstdint>

#define B_ 16
#define L_ 2048
#define D_ 1024
#define BLROWS (B_ * L_)                 // 32768
#define QK_SCALE 0.08838834764831845f    // 1/sqrt(1024/8)

typedef unsigned short u16;
typedef __attribute__((ext_vector_type(8))) __bf16 bf16x8;
typedef __attribute__((ext_vector_type(4))) float f32x4;
typedef __attribute__((ext_vector_type(4))) unsigned int u32x4;
typedef __attribute__((ext_vector_type(4))) u16 u16x4;

__device__ __forceinline__ u16 f2bf(float f) {
  unsigned u = __builtin_bit_cast(unsigned, f);
  u += 0x7fffu + ((u >> 16) & 1u);   // RNE (inputs are finite/normal)
  return (u16)(u >> 16);
}
__device__ __forceinline__ float bf2f(unsigned hu) {
  return __builtin_bit_cast(float, hu << 16);
}

// global -> LDS direct copy, 16B per lane. LDS dest must be wave-uniform base;
// HW writes base + lane*16 (CK-style addrspace casts).
__device__ __forceinline__ void gll16(const void* g, void* l) {
  auto gp = reinterpret_cast<const __attribute__((address_space(1))) unsigned int*>(
      reinterpret_cast<uintptr_t>(g));
  auto lp = reinterpret_cast<__attribute__((address_space(3))) unsigned int*>(
      reinterpret_cast<uintptr_t>(l));
  __builtin_amdgcn_global_load_lds(gp, lp, 16, 0, 0);
}

// ---------------- elementwise fp32 -> bf16 ----------------
typedef __attribute__((ext_vector_type(4))) float fv4;
__global__ void convert_bf16(const fv4* __restrict__ in, u16x4* __restrict__ out, int n4) {
  int i = blockIdx.x * blockDim.x + threadIdx.x;
  const int stride = gridDim.x * blockDim.x;
  for (; i < n4; i += stride) {
    fv4 v = in[i];
    u16x4 o;
    o.x = f2bf(v.x); o.y = f2bf(v.y); o.z = f2bf(v.z); o.w = f2bf(v.w);
    out[i] = o;
  }
}

// ---------------- 1024x1024 transpose + convert (weights) ----------------
__global__ void transpose_convert_1k(const float* __restrict__ W, u16* __restrict__ WT) {
  __shared__ float tile[32][33];
  const int bx = blockIdx.x * 32;
  const int by = blockIdx.y * 32;
  const int tx = threadIdx.x & 31;
  const int ty = threadIdx.x >> 5;   // 0..7
#pragma unroll
  for (int j = 0; j < 4; ++j) {
    const int r = ty + j * 8;
    tile[r][tx] = W[(size_t)(by + r) * 1024 + bx + tx];
  }
  __syncthreads();
#pragma unroll
  for (int j = 0; j < 4; ++j) {
    const int r = ty + j * 8;
    // WT[bx+r][by+tx] = W[by+tx][bx+r]
    WT[(size_t)(bx + r) * 1024 + by + tx] = f2bf(tile[tx][r]);
  }
}

// ---------------- row softmax over 2048 bf16, in place ----------------
__global__ void softmax_rows(u16* __restrict__ S) {
  const size_t row = blockIdx.x;
  u32x4* p = (u32x4*)(S + row * 2048);
  const int t = threadIdx.x;
  u32x4 v = p[t];
  unsigned vv[4] = {v.x, v.y, v.z, v.w};
  float x[8];
#pragma unroll
  for (int i = 0; i < 4; ++i) {
    x[2 * i]     = bf2f(vv[i] & 0xffffu);
    x[2 * i + 1] = bf2f(vv[i] >> 16);
  }
  float m = x[0];
#pragma unroll
  for (int i = 1; i < 8; ++i) m = fmaxf(m, x[i]);
#pragma unroll
  for (int off = 32; off > 0; off >>= 1) m = fmaxf(m, __shfl_xor(m, off));
  __shared__ float red[4];
  const int w = t >> 6, l = t & 63;
  if (l == 0) red[w] = m;
  __syncthreads();
  m = fmaxf(fmaxf(red[0], red[1]), fmaxf(red[2], red[3]));
  float e[8], s = 0.f;
#pragma unroll
  for (int i = 0; i < 8; ++i) { e[i] = __expf(x[i] - m); s += e[i]; }
#pragma unroll
  for (int off = 32; off > 0; off >>= 1) s += __shfl_xor(s, off);
  __syncthreads();
  if (l == 0) red[w] = s;
  __syncthreads();
  s = red[0] + red[1] + red[2] + red[3];
  const float inv = 1.0f / s;
  unsigned oo[4];
#pragma unroll
  for (int i = 0; i < 4; ++i) {
    oo[i] = (unsigned)f2bf(e[2 * i] * inv) | ((unsigned)f2bf(e[2 * i + 1] * inv) << 16);
  }
  u32x4 o; o.x = oo[0]; o.y = oo[1]; o.z = oo[2]; o.w = oo[3];
  p[t] = o;
}

// ---------------- NT GEMM (m97 structure): C[m][n] = sum_k A[m][k]*B[n][k] ----------------
// 128x128 tile, BK=32, 256 threads (4 waves, each a 64x64 quadrant), 16x16x32 bf16 MFMA.
// BIAS_MODE: 0 none, 1 per-col(n), 2 per-row(m). OUT_BF16: 1 bf16 out, 0 fp32 out.
template <int OUT_BF16, int BIAS_MODE, int RESID>
__global__ void gemm_nt(const u16* __restrict__ A, const u16* __restrict__ Bm,
                        void* __restrict__ Cv, const float* __restrict__ bias,
                        const float* __restrict__ resid, int M, int N, int K, float scale,
                        long long sA, long long sB, long long sC) {
  __shared__ alignas(16) u16 lsA[128 * 32];
  __shared__ alignas(16) u16 lsB[128 * 32];

  const int z = blockIdx.z;
  A  += (long long)z * sA;
  Bm += (long long)z * sB;

  const int n0 = blockIdx.x * 128;
  const int m0 = blockIdx.y * 128;

  const int t = threadIdx.x;
  const int w = t >> 6;
  const int l = t & 63;
  const int lr = l & 15;   // fragment row/col within 16
  const int lk = l >> 4;   // k-octet group 0..3
  const int wr = w >> 1;   // wave quadrant row
  const int wc = w & 1;    // wave quadrant col

  // staging: thread t covers tile row t/4 (and +64), cols (t%4)*8 .. +7
  const int srow = t >> 2;
  const int scol = (t & 3) * 8;
  const u16* ga0 = A + (long long)(m0 + srow) * K + scol;
  const u16* ga1 = ga0 + (long long)64 * K;
  const u16* gb0 = Bm + (long long)(n0 + srow) * K + scol;
  const u16* gb1 = gb0 + (long long)64 * K;
  char* lwa = (char*)lsA + w * 1024;   // wave-uniform LDS bases
  char* lwb = (char*)lsB + w * 1024;

  f32x4 acc[4][4];
#pragma unroll
  for (int i = 0; i < 4; ++i)
#pragma unroll
    for (int j = 0; j < 4; ++j) acc[i][j] = f32x4{0.f, 0.f, 0.f, 0.f};

  for (int k0 = 0; k0 < K; k0 += 32) {
    __syncthreads();                    // protect LDS from previous iter's readers
    gll16(ga0 + k0, lwa);
    gll16(ga1 + k0, lwa + 4096);
    gll16(gb0 + k0, lwb);
    gll16(gb1 + k0, lwb + 4096);
    __syncthreads();                    // drains vmcnt: staging complete

    bf16x8 af[4], bfr[4];
#pragma unroll
    for (int mi = 0; mi < 4; ++mi)
      af[mi] = __builtin_bit_cast(
          bf16x8, *(const u32x4*)&lsA[(wr * 64 + mi * 16 + lr) * 32 + lk * 8]);
#pragma unroll
    for (int ni = 0; ni < 4; ++ni)
      bfr[ni] = __builtin_bit_cast(
          bf16x8, *(const u32x4*)&lsB[(wc * 64 + ni * 16 + lr) * 32 + lk * 8]);
#pragma unroll
    for (int mi = 0; mi < 4; ++mi)
#pragma unroll
      for (int ni = 0; ni < 4; ++ni)
        acc[mi][ni] =
            __builtin_amdgcn_mfma_f32_16x16x32_bf16(af[mi], bfr[ni], acc[mi][ni], 0, 0, 0);
  }

  // epilogue: C row = (l>>4)*4 + reg, col = l&15 (m89-verified layout)
#pragma unroll
  for (int mi = 0; mi < 4; ++mi) {
#pragma unroll
    for (int i = 0; i < 4; ++i) {
      const int grow = m0 + wr * 64 + mi * 16 + lk * 4 + i;
#pragma unroll
      for (int ni = 0; ni < 4; ++ni) {
        const int gcol = n0 + wc * 64 + ni * 16 + lr;
        float v = acc[mi][ni][i] * scale;
        if (BIAS_MODE == 1) v += bias[gcol];
        if (BIAS_MODE == 2) v += bias[grow];
        if (RESID) v += resid[(long long)grow * N + gcol];
        const long long cidx = (long long)z * sC + (long long)grow * N + gcol;
        if (OUT_BF16) ((u16*)Cv)[cidx] = f2bf(v);
        else          ((float*)Cv)[cidx] = v;
      }
    }
  }
}

// ---------------- launch ----------------
extern "C" void kernel_launch(void* const* d_in, const int* in_sizes, int n_in,
                              void* d_out, int out_size, void* d_ws, size_t ws_size,
                              hipStream_t stream) {
  const float* query = (const float*)d_in[0];
  const float* key_  = (const float*)d_in[1];
  const float* value = (const float*)d_in[2];
  const float* Wq = (const float*)d_in[3];
  const float* bq = (const float*)d_in[4];
  const float* Wk = (const float*)d_in[5];
  const float* bk = (const float*)d_in[6];
  const float* Wv = (const float*)d_in[7];
  const float* bv = (const float*)d_in[8];
  const float* Wo = (const float*)d_in[9];
  const float* bo = (const float*)d_in[10];
  float* out = (float*)d_out;

  char* ws = (char*)d_ws;
  // layout (bytes): xq,xk,xv: 64MB each; 4 weights: 2MB each; qb,kb,vt: 64MB each.
  // S (128MB) reuses xq+xk after they die; ctx (64MB) reuses xv. Peak = 392 MiB.
  u16* xq  = (u16*)(ws + 0);
  u16* xk  = (u16*)(ws + 67108864);
  u16* xv  = (u16*)(ws + 134217728);
  u16* wqt = (u16*)(ws + 201326592);
  u16* wkt = (u16*)(ws + 203423744);
  u16* wvt = (u16*)(ws + 205520896);
  u16* wot = (u16*)(ws + 207618048);
  u16* qb  = (u16*)(ws + 209715200);
  u16* kb  = (u16*)(ws + 276824064);
  u16* vt  = (u16*)(ws + 343932928);
  u16* sp  = (u16*)(ws + 0);           // [16][2048][2048] bf16
  u16* ctx = (u16*)(ws + 134217728);   // [32768][1024] bf16

  const dim3 blk(256);
  const int n4 = BLROWS * D_ / 4;

  convert_bf16<<<2048, blk, 0, stream>>>((const fv4*)query, (u16x4*)xq, n4);
  convert_bf16<<<2048, blk, 0, stream>>>((const fv4*)key_,  (u16x4*)xk, n4);
  convert_bf16<<<2048, blk, 0, stream>>>((const fv4*)value, (u16x4*)xv, n4);
  transpose_convert_1k<<<dim3(32, 32), blk, 0, stream>>>(Wq, wqt);
  transpose_convert_1k<<<dim3(32, 32), blk, 0, stream>>>(Wk, wkt);
  transpose_convert_1k<<<dim3(32, 32), blk, 0, stream>>>(Wv, wvt);
  transpose_convert_1k<<<dim3(32, 32), blk, 0, stream>>>(Wo, wot);

  // Q = xq @ WqT^T + bq   [32768 x 1024]
  gemm_nt<1, 1, 0><<<dim3(8, 256, 1), blk, 0, stream>>>(
      xq, wqt, qb, bq, nullptr, BLROWS, D_, D_, 1.0f, 0, 0, 0);
  // K = xk @ WkT^T + bk
  gemm_nt<1, 1, 0><<<dim3(8, 256, 1), blk, 0, stream>>>(
      xk, wkt, kb, bk, nullptr, BLROWS, D_, D_, 1.0f, 0, 0, 0);
  // VT_b[e][l] = sum_d WvT[e][d]*value_b[l][d] + bv[e]   [1024 x 2048] per batch
  gemm_nt<1, 2, 0><<<dim3(16, 8, B_), blk, 0, stream>>>(
      wvt, xv, vt, bv, nullptr, D_, L_, D_, 1.0f,
      0, (long long)L_ * D_, (long long)D_ * L_);
  // S_b = Q_b @ K_b^T * scale   [2048 x 2048] per batch
  gemm_nt<1, 0, 0><<<dim3(16, 16, B_), blk, 0, stream>>>(
      qb, kb, sp, nullptr, nullptr, L_, L_, D_, QK_SCALE,
      (long long)L_ * D_, (long long)L_ * D_, (long long)L_ * L_);
  // P = softmax(S) rows, in place
  softmax_rows<<<BLROWS, blk, 0, stream>>>(sp);
  // ctx_b = P_b @ VT_b^T   [2048 x 1024] per batch
  gemm_nt<1, 0, 0><<<dim3(8, 16, B_), blk, 0, stream>>>(
      sp, vt, ctx, nullptr, nullptr, L_, D_, L_, 1.0f,
      (long long)L_ * L_, (long long)D_ * L_, (long long)L_ * D_);
  // out = ctx @ WoT^T + bo + residual(query)   fp32 [32768 x 1024]
  gemm_nt<0, 1, 1><<<dim3(8, 256, 1), blk, 0, stream>>>(
      ctx, wot, out, bo, query, BLROWS, D_, D_, 1.0f, 0, 0, 0);

  (void)in_sizes; (void)n_in; (void)out_size; (void)ws_size;
}

// Round 3
// 1069.875 us; speedup vs baseline: 1.1630x; 1.1630x over previous
//
#include <hip/hip_runtime.h>
#include <cstdint>

#define B_ 16
#define L_ 2048
#define D_ 1024
#define BLROWS (B_ * L_)                 // 32768
#define QK_SCALE 0.08838834764831845f    // 1/sqrt(1024/8)

typedef unsigned short u16;
typedef __attribute__((ext_vector_type(8))) __bf16 bf16x8;
typedef __attribute__((ext_vector_type(4))) float f32x4;
typedef __attribute__((ext_vector_type(4))) unsigned int u32x4;
typedef __attribute__((ext_vector_type(4))) u16 u16x4;

__device__ __forceinline__ u16 f2bf(float f) {
  unsigned u = __builtin_bit_cast(unsigned, f);
  u += 0x7fffu + ((u >> 16) & 1u);   // RNE
  return (u16)(u >> 16);
}
__device__ __forceinline__ float bf2f(unsigned hu) {
  return __builtin_bit_cast(float, hu << 16);
}

// global -> LDS direct copy, 16B per lane. LDS dest wave-uniform base; HW adds lane*16.
__device__ __forceinline__ void gll16(const void* g, void* l) {
  auto gp = reinterpret_cast<const __attribute__((address_space(1))) unsigned int*>(
      reinterpret_cast<uintptr_t>(g));
  auto lp = reinterpret_cast<__attribute__((address_space(3))) unsigned int*>(
      reinterpret_cast<uintptr_t>(l));
  __builtin_amdgcn_global_load_lds(gp, lp, 16, 0, 0);
}

// ---------------- elementwise fp32 -> bf16 ----------------
typedef __attribute__((ext_vector_type(4))) float fv4;
__global__ void convert_bf16(const fv4* __restrict__ in, u16x4* __restrict__ out, int n4) {
  int i = blockIdx.x * blockDim.x + threadIdx.x;
  const int stride = gridDim.x * blockDim.x;
  for (; i < n4; i += stride) {
    fv4 v = in[i];
    u16x4 o;
    o.x = f2bf(v.x); o.y = f2bf(v.y); o.z = f2bf(v.z); o.w = f2bf(v.w);
    out[i] = o;
  }
}

// ---------------- 1024x1024 transpose + convert (weights) ----------------
__global__ void transpose_convert_1k(const float* __restrict__ W, u16* __restrict__ WT) {
  __shared__ float tile[32][33];
  const int bx = blockIdx.x * 32;
  const int by = blockIdx.y * 32;
  const int tx = threadIdx.x & 31;
  const int ty = threadIdx.x >> 5;
#pragma unroll
  for (int j = 0; j < 4; ++j) {
    const int r = ty + j * 8;
    tile[r][tx] = W[(size_t)(by + r) * 1024 + bx + tx];
  }
  __syncthreads();
#pragma unroll
  for (int j = 0; j < 4; ++j) {
    const int r = ty + j * 8;
    WT[(size_t)(bx + r) * 1024 + by + tx] = f2bf(tile[tx][r]);
  }
}

// ---------------- row softmax over 2048 bf16, in place ----------------
__global__ void softmax_rows(u16* __restrict__ S) {
  const size_t row = blockIdx.x;
  u32x4* p = (u32x4*)(S + row * 2048);
  const int t = threadIdx.x;
  u32x4 v = p[t];
  unsigned vv[4] = {v.x, v.y, v.z, v.w};
  float x[8];
#pragma unroll
  for (int i = 0; i < 4; ++i) {
    x[2 * i]     = bf2f(vv[i] & 0xffffu);
    x[2 * i + 1] = bf2f(vv[i] >> 16);
  }
  float m = x[0];
#pragma unroll
  for (int i = 1; i < 8; ++i) m = fmaxf(m, x[i]);
#pragma unroll
  for (int off = 32; off > 0; off >>= 1) m = fmaxf(m, __shfl_xor(m, off));
  __shared__ float red[4];
  const int w = t >> 6, l = t & 63;
  if (l == 0) red[w] = m;
  __syncthreads();
  m = fmaxf(fmaxf(red[0], red[1]), fmaxf(red[2], red[3]));
  float e[8], s = 0.f;
#pragma unroll
  for (int i = 0; i < 8; ++i) { e[i] = __expf(x[i] - m); s += e[i]; }
#pragma unroll
  for (int off = 32; off > 0; off >>= 1) s += __shfl_xor(s, off);
  __syncthreads();
  if (l == 0) red[w] = s;
  __syncthreads();
  s = red[0] + red[1] + red[2] + red[3];
  const float inv = 1.0f / s;
  unsigned oo[4];
#pragma unroll
  for (int i = 0; i < 4; ++i) {
    oo[i] = (unsigned)f2bf(e[2 * i] * inv) | ((unsigned)f2bf(e[2 * i + 1] * inv) << 16);
  }
  u32x4 o; o.x = oo[0]; o.y = oo[1]; o.z = oo[2]; o.w = oo[3];
  p[t] = o;
}

// ================= 256x256 phase-split NT GEMM =================
// C[m][n] = sum_k A[m][k]*B[n][k].  512 threads = 8 waves (2M x 4N),
// BK=64, LDS 2 bufs x 4 half-tiles[128][64] (A0,A1,B0,B1), T2 slot-swizzle,
// per-K-tile: 4 phases x 16 MFMA, single counted-drain boundary, T5 setprio,
// T1 bijective XCD grid swizzle.
// Swizzle (involution): LDS(row, slot') holds global slot = slot' ^ (row&7).

#define MFMA16(QM, QN, BF)                                                    \
  _Pragma("unroll") for (int mf = 0; mf < 4; ++mf)                            \
  _Pragma("unroll") for (int nf = 0; nf < 2; ++nf)                            \
  _Pragma("unroll") for (int kk = 0; kk < 2; ++kk)                            \
      acc[(QM)*4 + mf][(QN)*2 + nf] = __builtin_amdgcn_mfma_f32_16x16x32_bf16( \
          af[mf][kk], BF[nf][kk], acc[(QM)*4 + mf][(QN)*2 + nf], 0, 0, 0);

template <int OUT_BF16, int BIAS_MODE, int RESID>
__global__ __launch_bounds__(512) void gemm8(
    const u16* __restrict__ A, const u16* __restrict__ Bm, void* __restrict__ Cv,
    const float* __restrict__ bias, const float* __restrict__ resid,
    int N, int K, float scale, long long sA, long long sB, long long sC,
    int gm, int gn) {
  __shared__ alignas(16) u16 lds[2][4][128 * 64];   // 128 KiB

  // T1: bijective XCD swizzle (m204), then decode z / mtile / ntile
  const int nwg = gridDim.x;
  const int wg = blockIdx.x;
  const int q = nwg >> 3, rr = nwg & 7;
  const int xcd = wg & 7, idx = wg >> 3;
  const int wgid = (xcd < rr ? xcd * (q + 1) : rr * (q + 1) + (xcd - rr) * q) + idx;
  const int z = wgid / (gm * gn);
  const int rem = wgid - z * gm * gn;
  const int my = rem / gn;
  const int nx = rem - my * gn;
  const int m0 = my * 256, n0 = nx * 256;

  A  += (long long)z * sA;
  Bm += (long long)z * sB;

  const int t = threadIdx.x;
  const int w = t >> 6;          // wave 0..7
  const int l = t & 63;
  const int wm = w >> 2;         // 0..1 : row half (128 rows)
  const int wn = w & 3;          // 0..3 : col quarter (64 cols)
  const int lr = l & 15;
  const int lk = l >> 4;

  // staging: thread covers (row r, swizzled slot) of each half-tile, 2 issues (i=0,1)
  const int r  = t >> 3;                     // 0..63
  const int sl = (t & 7) ^ (r & 7);          // pre-swizzled source slot
  const u16* pa00 = A  + (long long)(m0 +   0 + r) * K + sl * 8;
  const u16* pa01 = A  + (long long)(m0 +  64 + r) * K + sl * 8;
  const u16* pa10 = A  + (long long)(m0 + 128 + r) * K + sl * 8;
  const u16* pa11 = A  + (long long)(m0 + 192 + r) * K + sl * 8;
  const u16* pb00 = Bm + (long long)(n0 +   0 + r) * K + sl * 8;
  const u16* pb01 = Bm + (long long)(n0 +  64 + r) * K + sl * 8;
  const u16* pb10 = Bm + (long long)(n0 + 128 + r) * K + sl * 8;
  const u16* pb11 = Bm + (long long)(n0 + 192 + r) * K + sl * 8;
  const int wo = w * 512;                    // u16 offset of this wave's 1KB chunk

#define STAGE_TILE_A(LB, KT)                         \
  gll16(pa00 + (KT)*64, (LB) + 0 * 8192 +        wo); \
  gll16(pa01 + (KT)*64, (LB) + 0 * 8192 + 4096 + wo); \
  gll16(pa10 + (KT)*64, (LB) + 1 * 8192 +        wo); \
  gll16(pa11 + (KT)*64, (LB) + 1 * 8192 + 4096 + wo);
#define STAGE_TILE_B(LB, KT)                         \
  gll16(pb00 + (KT)*64, (LB) + 2 * 8192 +        wo); \
  gll16(pb01 + (KT)*64, (LB) + 2 * 8192 + 4096 + wo); \
  gll16(pb10 + (KT)*64, (LB) + 3 * 8192 +        wo); \
  gll16(pb11 + (KT)*64, (LB) + 3 * 8192 + 4096 + wo);

  f32x4 acc[8][4];
#pragma unroll
  for (int i = 0; i < 8; ++i)
#pragma unroll
    for (int j = 0; j < 4; ++j) acc[i][j] = f32x4{0.f, 0.f, 0.f, 0.f};

  // reader swizzled 16B-slot byte columns (u16 units), kk = 0,1
  const int cs0 = ((0 + lk) ^ (lr & 7)) * 8;
  const int cs1 = ((4 + lk) ^ (lr & 7)) * 8;
  const u16* LA = &lds[0][wm][0];              // this wave's A chunk, buf stride 4*8192
  const u16* LB_ = &lds[0][2 + (wn >> 1)][0];  // this wave's B chunk
  const int brow = (wn & 1) * 64 + lr;         // B row base within chunk

  // prologue: stage tile 0 into buf 0, drain, publish
  {
    u16* Lb = &lds[0][0][0];
    STAGE_TILE_A(Lb, 0)
    STAGE_TILE_B(Lb, 0)
  }
  asm volatile("s_waitcnt vmcnt(0)" ::: "memory");
  __builtin_amdgcn_s_barrier();
  __builtin_amdgcn_sched_barrier(0);

  const int NT = K >> 6;
  for (int kt = 0; kt < NT; ++kt) {
    const int br = kt & 1, bs = br ^ 1;
    const bool pf = (kt + 1 < NT);
    const u16* Ra = LA + br * 32768;   // 4*8192 u16 per buffer
    const u16* Rb = LB_ + br * 32768;
    u16* Lb = &lds[bs][0][0];

    bf16x8 af[4][2], bf0[2][2], bf1[2][2];

    // ---- phase 0: stage next A; read af(qm=0) + bf(qn=0); MFMA quad(0,0)
    if (pf) { STAGE_TILE_A(Lb, kt + 1) }
#pragma unroll
    for (int mf = 0; mf < 4; ++mf) {
      const int row = mf * 16 + lr;
      af[mf][0] = __builtin_bit_cast(bf16x8, *(const u32x4*)&Ra[row * 64 + cs0]);
      af[mf][1] = __builtin_bit_cast(bf16x8, *(const u32x4*)&Ra[row * 64 + cs1]);
    }
#pragma unroll
    for (int nf = 0; nf < 2; ++nf) {
      const int row = brow + nf * 16;
      bf0[nf][0] = __builtin_bit_cast(bf16x8, *(const u32x4*)&Rb[row * 64 + cs0]);
      bf0[nf][1] = __builtin_bit_cast(bf16x8, *(const u32x4*)&Rb[row * 64 + cs1]);
    }
    __builtin_amdgcn_s_barrier();
    __builtin_amdgcn_s_setprio(1);
    MFMA16(0, 0, bf0)
    __builtin_amdgcn_s_setprio(0);
    __builtin_amdgcn_s_barrier();

    // ---- phase 1: stage next B; read bf(qn=1); MFMA quad(0,1)
    if (pf) { STAGE_TILE_B(Lb, kt + 1) }
#pragma unroll
    for (int nf = 0; nf < 2; ++nf) {
      const int row = brow + 32 + nf * 16;
      bf1[nf][0] = __builtin_bit_cast(bf16x8, *(const u32x4*)&Rb[row * 64 + cs0]);
      bf1[nf][1] = __builtin_bit_cast(bf16x8, *(const u32x4*)&Rb[row * 64 + cs1]);
    }
    __builtin_amdgcn_s_barrier();
    __builtin_amdgcn_s_setprio(1);
    MFMA16(0, 1, bf1)
    __builtin_amdgcn_s_setprio(0);
    __builtin_amdgcn_s_barrier();

    // ---- phase 2: read af(qm=1); MFMA quad(1,1)
#pragma unroll
    for (int mf = 0; mf < 4; ++mf) {
      const int row = 64 + mf * 16 + lr;
      af[mf][0] = __builtin_bit_cast(bf16x8, *(const u32x4*)&Ra[row * 64 + cs0]);
      af[mf][1] = __builtin_bit_cast(bf16x8, *(const u32x4*)&Ra[row * 64 + cs1]);
    }
    __builtin_amdgcn_s_barrier();
    __builtin_amdgcn_s_setprio(1);
    MFMA16(1, 1, bf1)
    __builtin_amdgcn_s_setprio(0);
    __builtin_amdgcn_s_barrier();

    // ---- phase 3: MFMA quad(1,0), no reads
    __builtin_amdgcn_s_setprio(1);
    MFMA16(1, 0, bf0)
    __builtin_amdgcn_s_setprio(0);

    // ---- boundary: drain own staging loads, publish buffer
    if (pf) { asm volatile("s_waitcnt vmcnt(0)" ::: "memory"); }
    __builtin_amdgcn_s_barrier();
    __builtin_amdgcn_sched_barrier(0);
  }

  // epilogue: acc[mi][nj] -> C rows (mi>>2)*64+(mi&3)*16+lk*4+i, cols (nj>>1)*32+(nj&1)*16+lr
  const int crow0 = m0 + wm * 128;
  const int ccol0 = n0 + wn * 64;
#pragma unroll
  for (int mi = 0; mi < 8; ++mi) {
#pragma unroll
    for (int i = 0; i < 4; ++i) {
      const int grow = crow0 + (mi >> 2) * 64 + (mi & 3) * 16 + lk * 4 + i;
#pragma unroll
      for (int nj = 0; nj < 4; ++nj) {
        const int gcol = ccol0 + (nj >> 1) * 32 + (nj & 1) * 16 + lr;
        float v = acc[mi][nj][i] * scale;
        if (BIAS_MODE == 1) v += bias[gcol];
        if (BIAS_MODE == 2) v += bias[grow];
        if (RESID) v += resid[(long long)grow * N + gcol];
        const long long cidx = (long long)z * sC + (long long)grow * N + gcol;
        if (OUT_BF16) ((u16*)Cv)[cidx] = f2bf(v);
        else          ((float*)Cv)[cidx] = v;
      }
    }
  }
}

// ---------------- launch ----------------
extern "C" void kernel_launch(void* const* d_in, const int* in_sizes, int n_in,
                              void* d_out, int out_size, void* d_ws, size_t ws_size,
                              hipStream_t stream) {
  const float* query = (const float*)d_in[0];
  const float* key_  = (const float*)d_in[1];
  const float* value = (const float*)d_in[2];
  const float* Wq = (const float*)d_in[3];
  const float* bq = (const float*)d_in[4];
  const float* Wk = (const float*)d_in[5];
  const float* bk = (const float*)d_in[6];
  const float* Wv = (const float*)d_in[7];
  const float* bv = (const float*)d_in[8];
  const float* Wo = (const float*)d_in[9];
  const float* bo = (const float*)d_in[10];
  float* out = (float*)d_out;

  char* ws = (char*)d_ws;
  u16* xq  = (u16*)(ws + 0);
  u16* xk  = (u16*)(ws + 67108864);
  u16* xv  = (u16*)(ws + 134217728);
  u16* wqt = (u16*)(ws + 201326592);
  u16* wkt = (u16*)(ws + 203423744);
  u16* wvt = (u16*)(ws + 205520896);
  u16* wot = (u16*)(ws + 207618048);
  u16* qb  = (u16*)(ws + 209715200);
  u16* kb  = (u16*)(ws + 276824064);
  u16* vt  = (u16*)(ws + 343932928);
  u16* sp  = (u16*)(ws + 0);           // [16][2048][2048] bf16 (reuses xq+xk)
  u16* ctx = (u16*)(ws + 134217728);   // [32768][1024] bf16 (reuses xv)

  const dim3 blk(256);
  const dim3 blk8(512);
  const int n4 = BLROWS * D_ / 4;

  convert_bf16<<<2048, blk, 0, stream>>>((const fv4*)query, (u16x4*)xq, n4);
  convert_bf16<<<2048, blk, 0, stream>>>((const fv4*)key_,  (u16x4*)xk, n4);
  convert_bf16<<<2048, blk, 0, stream>>>((const fv4*)value, (u16x4*)xv, n4);
  transpose_convert_1k<<<dim3(32, 32), blk, 0, stream>>>(Wq, wqt);
  transpose_convert_1k<<<dim3(32, 32), blk, 0, stream>>>(Wk, wkt);
  transpose_convert_1k<<<dim3(32, 32), blk, 0, stream>>>(Wv, wvt);
  transpose_convert_1k<<<dim3(32, 32), blk, 0, stream>>>(Wo, wot);

  // Q = xq @ WqT^T + bq   [32768 x 1024]  gm=128 gn=4 -> 512 wgs
  gemm8<1, 1, 0><<<dim3(512), blk8, 0, stream>>>(
      xq, wqt, qb, bq, nullptr, D_, D_, 1.0f, 0, 0, 0, 128, 4);
  // K = xk @ WkT^T + bk
  gemm8<1, 1, 0><<<dim3(512), blk8, 0, stream>>>(
      xk, wkt, kb, bk, nullptr, D_, D_, 1.0f, 0, 0, 0, 128, 4);
  // VT_b[e][l] = sum_d WvT[e][d]*value_b[l][d] + bv[e]  [1024 x 2048] x16  gm=4 gn=8
  gemm8<1, 2, 0><<<dim3(512), blk8, 0, stream>>>(
      wvt, xv, vt, bv, nullptr, L_, D_, 1.0f,
      0, (long long)L_ * D_, (long long)D_ * L_, 4, 8);
  // S_b = Q_b @ K_b^T * scale  [2048 x 2048] x16  gm=8 gn=8 -> 1024 wgs
  gemm8<1, 0, 0><<<dim3(1024), blk8, 0, stream>>>(
      qb, kb, sp, nullptr, nullptr, L_, D_, QK_SCALE,
      (long long)L_ * D_, (long long)L_ * D_, (long long)L_ * L_, 8, 8);
  // P = softmax(S) rows, in place
  softmax_rows<<<BLROWS, blk, 0, stream>>>(sp);
  // ctx_b = P_b @ VT_b^T  [2048 x 1024] x16  gm=8 gn=4 -> 512 wgs
  gemm8<1, 0, 0><<<dim3(512), blk8, 0, stream>>>(
      sp, vt, ctx, nullptr, nullptr, D_, L_, 1.0f,
      (long long)L_ * L_, (long long)D_ * L_, (long long)L_ * D_, 8, 4);
  // out = ctx @ WoT^T + bo + residual(query)  fp32 [32768 x 1024]
  gemm8<0, 1, 1><<<dim3(512), blk8, 0, stream>>>(
      ctx, wot, out, bo, query, D_, D_, 1.0f, 0, 0, 0, 128, 4);

  (void)in_sizes; (void)n_in; (void)out_size; (void)ws_size;
}